// Round 2
// baseline (111.376 us; speedup 1.0000x reference)
//
#include <hip/hip_runtime.h>
#include <hip/hip_bf16.h>

#define EPS 1e-7f

__device__ __forceinline__ float pers_elem(float p, float s, float w) {
    p = fminf(fmaxf(p, EPS), 1.0f - EPS);
    // logit
    float l = __logf(p / (1.0f - p));
    // scaled + biased logit
    float x = fmaf(l, s, w);
    // sigmoid
    return 1.0f / (1.0f + __expf(-x));
}

// One block per batch row b. Row = S*H floats (3200), processed as float4.
// H = 16: a float4 at float-offset j*4 covers h = (j*4)%16 .. +3, and since
// the thread stride (256 float4s = 1024 floats) is a multiple of 16, each
// thread's h-phase is loop-invariant -> hoist scale/bias loads out of loop.
__global__ __launch_bounds__(256) void PersonalizationLayer_30528627540712_kernel(
    const float* __restrict__ probs,
    const float* __restrict__ scale_table,
    const float* __restrict__ bias_table,
    const int*   __restrict__ user_idx,
    float*       __restrict__ out,
    int row4)   // row length in float4 units (S*H/4)
{
    const int b   = blockIdx.x;
    const int tid = threadIdx.x;
    const int u   = user_idx[b];

    // h-phase for this thread's float4s: (tid*4) % 16
    const int h0 = (tid & 3) * 4;
    const float4 s4 = *reinterpret_cast<const float4*>(&scale_table[(size_t)u * 16 + h0]);
    const float4 w4 = *reinterpret_cast<const float4*>(&bias_table [(size_t)u * 16 + h0]);

    const float4* __restrict__ in = reinterpret_cast<const float4*>(probs + (size_t)b * row4 * 4);
    float4*       __restrict__ o  = reinterpret_cast<float4*>(out + (size_t)b * row4 * 4);

    for (int j = tid; j < row4; j += 256) {
        float4 p = in[j];
        float4 r;
        r.x = pers_elem(p.x, s4.x, w4.x);
        r.y = pers_elem(p.y, s4.y, w4.y);
        r.z = pers_elem(p.z, s4.z, w4.z);
        r.w = pers_elem(p.w, s4.w, w4.w);
        o[j] = r;
    }
}

extern "C" void kernel_launch(void* const* d_in, const int* in_sizes, int n_in,
                              void* d_out, int out_size, void* d_ws, size_t ws_size,
                              hipStream_t stream) {
    const float* probs       = (const float*)d_in[0];
    const float* scale_table = (const float*)d_in[1];
    const float* bias_table  = (const float*)d_in[2];
    const int*   user_idx    = (const int*)d_in[3];
    float* out = (float*)d_out;

    const int B    = in_sizes[3];            // 4096
    const int row  = in_sizes[0] / B;        // S*H = 3200
    const int row4 = row / 4;                // 800

    PersonalizationLayer_30528627540712_kernel<<<B, 256, 0, stream>>>(
        probs, scale_table, bias_table, user_idx, out, row4);
}